// Round 9
// baseline (472.499 us; speedup 1.0000x reference)
//
#include <hip/hip_runtime.h>
#include <math.h>

#define NQ 4
#define NL 2
#define DIM 16          // 2^NQ
#define BATCH 16
#define CH 256
#define HW 16384        // 128*128
#define NBLK 1024       // 4 blocks/CU on 256 CUs -- all co-resident (pigeonhole)
#define SPB 4           // slices (b,c) per block, all same b

typedef float floatx4 __attribute__((ext_vector_type(4)));

// Persistent fused kernel: pool -> software grid barrier -> gate -> scale.
// Residency: slice 0 in VGPRs (64 regs), slice 1 low half in LDS (32 KB).
// __launch_bounds__(256,4) caps VGPRs at 128 -> 4 blocks/CU -> all 1024
// blocks co-resident -> the atomic-counter barrier cannot deadlock (R8-proven).
__global__ __launch_bounds__(256, 4) void fused_all(
    const float* __restrict__ x,
    const float* __restrict__ enc_w,   // [NQ, CH]
    const float* __restrict__ enc_b,   // [NQ]
    const float* __restrict__ qw,      // [NL, NQ, 3]
    const float* __restrict__ proj_w,  // [CH, NQ]
    const float* __restrict__ proj_b,  // [CH]
    float* __restrict__ out,
    float* __restrict__ pooled,        // ws: [BATCH*CH]
    unsigned* __restrict__ ctr)        // ws: barrier counter (memset 0 per call)
{
    const int tid = threadIdx.x;
    const int slice0 = blockIdx.x * SPB;    // 4 consecutive (b,c), same b
    const int b = slice0 >> 8;

    __shared__ floatx4 lds1[8 * 256];       // slice 1, k=0..7 (32 KB)
    __shared__ float part[SPB][4];
    __shared__ float sz[NQ];
    __shared__ float sevs[NQ];
    __shared__ float sgate[SPB];

    const floatx4* xs0 = (const floatx4*)(x + (size_t)(slice0 + 0) * HW);
    const floatx4* xs1 = (const floatx4*)(x + (size_t)(slice0 + 1) * HW);
    const floatx4* xs2 = (const floatx4*)(x + (size_t)(slice0 + 2) * HW);
    const floatx4* xs3 = (const floatx4*)(x + (size_t)(slice0 + 3) * HW);

    // ---------------- Phase 1: pool (4 interleaved streams, one sync) --------
    floatx4 v0[16];                          // slice 0 stays resident
    float a0 = 0.f, a1 = 0.f, a2 = 0.f, a3 = 0.f;
#pragma unroll
    for (int k = 0; k < 16; ++k) {
        v0[k] = xs0[tid + k * 256];
        floatx4 t1 = xs1[tid + k * 256];
        floatx4 t2 = xs2[tid + k * 256];
        floatx4 t3 = xs3[tid + k * 256];
        if (k < 8) lds1[k * 256 + tid] = t1;
        a0 += v0[k].x + v0[k].y + v0[k].z + v0[k].w;
        a1 += t1.x + t1.y + t1.z + t1.w;
        a2 += t2.x + t2.y + t2.z + t2.w;
        a3 += t3.x + t3.y + t3.z + t3.w;
    }
    {
        const int wid = tid >> 6, lane = tid & 63;
        float av[SPB] = {a0, a1, a2, a3};
#pragma unroll
        for (int s = 0; s < SPB; ++s) {
            float r = av[s];
#pragma unroll
            for (int off = 32; off > 0; off >>= 1) r += __shfl_down(r, off, 64);
            if (lane == 0) part[s][wid] = r;
        }
    }
    __syncthreads();
    if (tid < SPB)
        pooled[slice0 + tid] =
            (part[tid][0] + part[tid][1] + part[tid][2] + part[tid][3]) * (1.f / HW);

    // ---------------- Grid barrier (all 1024 blocks co-resident) -------------
    __syncthreads();
    if (tid == 0) {
        __threadfence();   // release pooled[] to device scope (cross-XCD)
        __hip_atomic_fetch_add(ctr, 1u, __ATOMIC_ACQ_REL, __HIP_MEMORY_SCOPE_AGENT);
        while (__hip_atomic_load(ctr, __ATOMIC_ACQUIRE, __HIP_MEMORY_SCOPE_AGENT) < (unsigned)NBLK)
            __builtin_amdgcn_s_sleep(8);
        __threadfence();   // acquire
    }
    __syncthreads();

    // ---------------- Phase 2: gate (redundant per block) --------------------
    {
        const int q = tid >> 6, lane = tid & 63;
        const float* prow = pooled + b * CH;
        float acc = 0.f;
#pragma unroll
        for (int j = 0; j < 4; ++j) {
            const int c = lane * 4 + j;
            acc += prow[c] * enc_w[q * CH + c];
        }
#pragma unroll
        for (int off = 32; off > 0; off >>= 1) acc += __shfl_down(acc, off, 64);
        if (lane == 0) sz[q] = tanhf(acc + enc_b[q]);
    }
    __syncthreads();

    if (tid == 0) {
        float re[DIM], im[DIM];
#pragma unroll
        for (int i = 0; i < DIM; ++i) { re[i] = 0.f; im[i] = 0.f; }
        re[0] = 1.f;

        // AngleEmbedding: RY(z_w) on wire w (wire 0 = MSB)
        for (int w = 0; w < NQ; ++w) {
            const float a = sz[w] * 0.5f;
            const float cc = cosf(a), ss = sinf(a);
            const int m = 1 << (3 - w);
#pragma unroll
            for (int i = 0; i < DIM; ++i) {
                if (i & m) continue;
                const int j = i | m;
                const float r0 = cc * re[i] - ss * re[j];
                const float i0 = cc * im[i] - ss * im[j];
                const float r1 = ss * re[i] + cc * re[j];
                const float i1 = ss * im[i] + cc * im[j];
                re[i] = r0; im[i] = i0; re[j] = r1; im[j] = i1;
            }
        }
        // StronglyEntanglingLayers
        for (int l = 0; l < NL; ++l) {
            for (int w = 0; w < NQ; ++w) {
                const float phi = qw[(l * NQ + w) * 3 + 0];
                const float th  = qw[(l * NQ + w) * 3 + 1];
                const float om  = qw[(l * NQ + w) * 3 + 2];
                const float ct = cosf(0.5f * th), st = sinf(0.5f * th);
                const float am = -0.5f * (phi + om);
                const float ad =  0.5f * (phi - om);
                const float emr = cosf(am), emi = sinf(am);
                const float edr = cosf(ad), edi = sinf(ad);
                const float u00r =  emr * ct, u00i =  emi * ct;
                const float u01r = -edr * st, u01i = -edi * st;
                const float u10r =  edr * st, u10i = -edi * st;
                const float u11r =  emr * ct, u11i = -emi * ct;
                const int m = 1 << (3 - w);
#pragma unroll
                for (int i = 0; i < DIM; ++i) {
                    if (i & m) continue;
                    const int j = i | m;
                    const float ar = re[i], ai = im[i], br = re[j], bi = im[j];
                    re[i] = u00r * ar - u00i * ai + u01r * br - u01i * bi;
                    im[i] = u00r * ai + u00i * ar + u01r * bi + u01i * br;
                    re[j] = u10r * ar - u10i * ai + u11r * br - u11i * bi;
                    im[j] = u10r * ai + u10i * ar + u11r * bi + u11i * br;
                }
            }
            const int r = (l % (NQ - 1)) + 1;
            for (int w = 0; w < NQ; ++w) {
                const int t = (w + r) % NQ;
                const int cm = 1 << (3 - w);
                const int tm = 1 << (3 - t);
#pragma unroll
                for (int i = 0; i < DIM; ++i) {
                    if ((i & cm) && !(i & tm)) {
                        const int j = i | tm;
                        float tr = re[i]; re[i] = re[j]; re[j] = tr;
                        float ti = im[i]; im[i] = im[j]; im[j] = ti;
                    }
                }
            }
        }
        float p[DIM];
#pragma unroll
        for (int i = 0; i < DIM; ++i) p[i] = re[i] * re[i] + im[i] * im[i];
        for (int w = 0; w < NQ; ++w) {
            const int m = 1 << (3 - w);
            float ev = 0.f;
#pragma unroll
            for (int i = 0; i < DIM; ++i) ev += (i & m) ? -p[i] : p[i];
            sevs[w] = ev;
        }
    }
    __syncthreads();

    if (tid < SPB) {
        const int c = (slice0 & 255) + tid;
        const float acc = sevs[0] * proj_w[c * NQ + 0] + sevs[1] * proj_w[c * NQ + 1] +
                          sevs[2] * proj_w[c * NQ + 2] + sevs[3] * proj_w[c * NQ + 3] +
                          proj_b[c];
        sgate[tid] = 1.f + 1.f / (1.f + expf(-acc));
    }
    __syncthreads();

    const float g0 = sgate[0], g1 = sgate[1], g2 = sgate[2], g3 = sgate[3];
    floatx4* os0 = (floatx4*)(out + (size_t)(slice0 + 0) * HW);
    floatx4* os1 = (floatx4*)(out + (size_t)(slice0 + 1) * HW);
    floatx4* os2 = (floatx4*)(out + (size_t)(slice0 + 2) * HW);
    floatx4* os3 = (floatx4*)(out + (size_t)(slice0 + 3) * HW);

    // ---------------- Phase 3: scale -----------------------------------------
    // slice 0 from registers (no re-read)
#pragma unroll
    for (int k = 0; k < 16; ++k)
        __builtin_nontemporal_store(v0[k] * g0, &os0[tid + k * 256]);
    // slice 1 low half from LDS (no re-read; each thread reads what it wrote)
#pragma unroll
    for (int k = 0; k < 8; ++k) {
        floatx4 t = lds1[k * 256 + tid];
        __builtin_nontemporal_store(t * g1, &os1[tid + k * 256]);
    }
    // streamed: slice 1 high half + slices 2,3 (5 independent chains/iter)
#pragma unroll
    for (int k = 0; k < 8; ++k) {
        floatx4 u1 = xs1[tid + (k + 8) * 256];
        floatx4 u2 = xs2[tid + k * 256];
        floatx4 u2b = xs2[tid + (k + 8) * 256];
        floatx4 u3 = xs3[tid + k * 256];
        floatx4 u3b = xs3[tid + (k + 8) * 256];
        __builtin_nontemporal_store(u1 * g1, &os1[tid + (k + 8) * 256]);
        __builtin_nontemporal_store(u2 * g2, &os2[tid + k * 256]);
        __builtin_nontemporal_store(u2b * g2, &os2[tid + (k + 8) * 256]);
        __builtin_nontemporal_store(u3 * g3, &os3[tid + k * 256]);
        __builtin_nontemporal_store(u3b * g3, &os3[tid + (k + 8) * 256]);
    }
}

extern "C" void kernel_launch(void* const* d_in, const int* in_sizes, int n_in,
                              void* d_out, int out_size, void* d_ws, size_t ws_size,
                              hipStream_t stream) {
    const float* x      = (const float*)d_in[0];
    const float* enc_w  = (const float*)d_in[1];
    const float* enc_b  = (const float*)d_in[2];
    const float* qw     = (const float*)d_in[3];
    const float* proj_w = (const float*)d_in[4];
    const float* proj_b = (const float*)d_in[5];
    float* out = (float*)d_out;

    float* pooled = (float*)d_ws;                       // [4096]
    unsigned* ctr = (unsigned*)(pooled + BATCH * CH);   // barrier counter

    hipMemsetAsync(ctr, 0, sizeof(unsigned), stream);   // reset barrier each call
    fused_all<<<NBLK, 256, 0, stream>>>(x, enc_w, enc_b, qw, proj_w, proj_b,
                                        out, pooled, ctr);
}

// Round 10
// 412.191 us; speedup vs baseline: 1.1463x; 1.1463x over previous
//
#include <hip/hip_runtime.h>
#include <math.h>

#define NQ 4
#define NL 2
#define DIM 16          // 2^NQ
#define BATCH 16
#define CH 256
#define HW 16384        // 128*128
#define NPOOL (BATCH * CH)   // 4096 pool blocks

typedef float floatx4 __attribute__((ext_vector_type(4)));

// ---- Kernel A: pool + (last block) gate -------------------------------------
// Each block pools one (b,c) slice. The LAST block to finish (atomic counter,
// agent scope -- no co-residency assumption, cannot deadlock) computes the
// encoder + 16 quantum circuits + all 4096 gates. Removes the serial
// gate_kernel dispatch and one launch gap.
__global__ void pool_gate_kernel(const float* __restrict__ x,
                                 const float* __restrict__ enc_w,   // [NQ, CH]
                                 const float* __restrict__ enc_b,   // [NQ]
                                 const float* __restrict__ qw,      // [NL, NQ, 3]
                                 const float* __restrict__ proj_w,  // [CH, NQ]
                                 const float* __restrict__ proj_b,  // [CH]
                                 float* __restrict__ pooled,        // ws [4096]
                                 float* __restrict__ gates1p,       // ws [4096]
                                 unsigned* __restrict__ ctr) {      // ws, memset 0
    const int bc = blockIdx.x;
    const floatx4* x4 = (const floatx4*)(x + (size_t)bc * HW);
    const int tid = threadIdx.x;

    float s = 0.f;
#pragma unroll
    for (int k = 0; k < 16; ++k) {
        floatx4 v = x4[tid + k * 256];
        s += v.x + v.y + v.z + v.w;
    }
#pragma unroll
    for (int off = 32; off > 0; off >>= 1) s += __shfl_down(s, off, 64);

    __shared__ float partial[4];
    __shared__ int is_last;
    if ((tid & 63) == 0) partial[tid >> 6] = s;
    __syncthreads();
    if (tid == 0) {
        pooled[bc] = (partial[0] + partial[1] + partial[2] + partial[3]) * (1.f / HW);
        __threadfence();   // release pooled[bc] to device scope
        const unsigned prev = __hip_atomic_fetch_add(ctr, 1u, __ATOMIC_ACQ_REL,
                                                     __HIP_MEMORY_SCOPE_AGENT);
        is_last = (prev == NPOOL - 1);
    }
    __syncthreads();
    if (!is_last) return;
    __threadfence();       // acquire: all blocks' pooled[] now visible

    // ---------------- gate phase (single last block, 256 threads) -----------
    __shared__ float sp[BATCH * CH];
    __shared__ float sz[BATCH][NQ];
    __shared__ float sref[BATCH][NQ];

    for (int i = tid; i < BATCH * CH; i += 256) sp[i] = pooled[i];
    __syncthreads();

    // z = tanh(pooled @ enc_w^T + enc_b)
    if (tid < BATCH * NQ) {
        const int b = tid >> 2, q = tid & 3;
        float acc = enc_b[q];
        for (int c = 0; c < CH; ++c) acc += sp[b * CH + c] * enc_w[q * CH + c];
        sz[b][q] = tanhf(acc);
    }
    __syncthreads();

    // statevector simulation: one thread per batch
    if (tid < BATCH) {
        const int b = tid;
        float re[DIM], im[DIM];
#pragma unroll
        for (int i = 0; i < DIM; ++i) { re[i] = 0.f; im[i] = 0.f; }
        re[0] = 1.f;

        // AngleEmbedding: RY(z_w) on wire w (wire 0 = MSB)
        for (int w = 0; w < NQ; ++w) {
            const float a = sz[b][w] * 0.5f;
            const float cc = cosf(a), ss = sinf(a);
            const int m = 1 << (3 - w);
#pragma unroll
            for (int i = 0; i < DIM; ++i) {
                if (i & m) continue;
                const int j = i | m;
                const float r0 = cc * re[i] - ss * re[j];
                const float i0 = cc * im[i] - ss * im[j];
                const float r1 = ss * re[i] + cc * re[j];
                const float i1 = ss * im[i] + cc * im[j];
                re[i] = r0; im[i] = i0; re[j] = r1; im[j] = i1;
            }
        }
        // StronglyEntanglingLayers
        for (int l = 0; l < NL; ++l) {
            for (int w = 0; w < NQ; ++w) {
                const float phi = qw[(l * NQ + w) * 3 + 0];
                const float th  = qw[(l * NQ + w) * 3 + 1];
                const float om  = qw[(l * NQ + w) * 3 + 2];
                const float ct = cosf(0.5f * th), st = sinf(0.5f * th);
                const float am = -0.5f * (phi + om);
                const float ad =  0.5f * (phi - om);
                const float emr = cosf(am), emi = sinf(am);
                const float edr = cosf(ad), edi = sinf(ad);
                const float u00r =  emr * ct, u00i =  emi * ct;
                const float u01r = -edr * st, u01i = -edi * st;
                const float u10r =  edr * st, u10i = -edi * st;
                const float u11r =  emr * ct, u11i = -emi * ct;
                const int m = 1 << (3 - w);
#pragma unroll
                for (int i = 0; i < DIM; ++i) {
                    if (i & m) continue;
                    const int j = i | m;
                    const float ar = re[i], ai = im[i], br = re[j], bi = im[j];
                    re[i] = u00r * ar - u00i * ai + u01r * br - u01i * bi;
                    im[i] = u00r * ai + u00i * ar + u01r * bi + u01i * br;
                    re[j] = u10r * ar - u10i * ai + u11r * br - u11i * bi;
                    im[j] = u10r * ai + u10i * ar + u11r * bi + u11i * br;
                }
            }
            const int r = (l % (NQ - 1)) + 1;
            for (int w = 0; w < NQ; ++w) {
                const int t = (w + r) % NQ;
                const int cm = 1 << (3 - w);
                const int tm = 1 << (3 - t);
#pragma unroll
                for (int i = 0; i < DIM; ++i) {
                    if ((i & cm) && !(i & tm)) {
                        const int j = i | tm;
                        float tr = re[i]; re[i] = re[j]; re[j] = tr;
                        float ti = im[i]; im[i] = im[j]; im[j] = ti;
                    }
                }
            }
        }
        float p[DIM];
#pragma unroll
        for (int i = 0; i < DIM; ++i) p[i] = re[i] * re[i] + im[i] * im[i];
        for (int w = 0; w < NQ; ++w) {
            const int m = 1 << (3 - w);
            float ev = 0.f;
#pragma unroll
            for (int i = 0; i < DIM; ++i) ev += (i & m) ? -p[i] : p[i];
            sref[b][w] = ev;
        }
    }
    __syncthreads();

    // gates1p[b,c] = 1 + sigmoid(refined @ proj_w^T + proj_b)
    {
        const int c = tid;
        const float pw0 = proj_w[c * NQ + 0], pw1 = proj_w[c * NQ + 1];
        const float pw2 = proj_w[c * NQ + 2], pw3 = proj_w[c * NQ + 3];
        const float pb = proj_b[c];
        for (int b = 0; b < BATCH; ++b) {
            const float acc = sref[b][0] * pw0 + sref[b][1] * pw1 +
                              sref[b][2] * pw2 + sref[b][3] * pw3 + pb;
            gates1p[b * CH + c] = 1.f + 1.f / (1.f + expf(-acc));
        }
    }
}

// ---- Kernel B: scale (proven R4 geometry) -----------------------------------
// Block owns 2048 consecutive float4 (within one (b,c) slice) -> g is a
// block-uniform scalar load; 8 independent loads then 8 nt stores.
__global__ void scale_kernel(const float* __restrict__ x,
                             const float* __restrict__ gates1p,
                             float* __restrict__ out) {
    const floatx4* x4 = (const floatx4*)x;
    floatx4* o4 = (floatx4*)out;
    const int base = blockIdx.x * 2048 + threadIdx.x;
    const float g = gates1p[blockIdx.x >> 1];   // 2 blocks per (b,c)
    floatx4 v[8];
#pragma unroll
    for (int k = 0; k < 8; ++k) v[k] = x4[base + k * 256];
#pragma unroll
    for (int k = 0; k < 8; ++k) {
        v[k] *= g;
        __builtin_nontemporal_store(v[k], &o4[base + k * 256]);
    }
}

extern "C" void kernel_launch(void* const* d_in, const int* in_sizes, int n_in,
                              void* d_out, int out_size, void* d_ws, size_t ws_size,
                              hipStream_t stream) {
    const float* x      = (const float*)d_in[0];
    const float* enc_w  = (const float*)d_in[1];
    const float* enc_b  = (const float*)d_in[2];
    const float* qw     = (const float*)d_in[3];
    const float* proj_w = (const float*)d_in[4];
    const float* proj_b = (const float*)d_in[5];
    float* out = (float*)d_out;

    float* pooled  = (float*)d_ws;                      // [4096]
    float* gates1p = pooled + NPOOL;                    // [4096]
    unsigned* ctr  = (unsigned*)(gates1p + NPOOL);      // last-block counter

    hipMemsetAsync(ctr, 0, sizeof(unsigned), stream);   // reset each call
    pool_gate_kernel<<<NPOOL, 256, 0, stream>>>(x, enc_w, enc_b, qw,
                                                proj_w, proj_b,
                                                pooled, gates1p, ctr);
    scale_kernel<<<8192, 256, 0, stream>>>(x, gates1p, out);
}

// Round 11
// 168.400 us; speedup vs baseline: 2.8058x; 2.4477x over previous
//
#include <hip/hip_runtime.h>
#include <math.h>

#define NQ 4
#define NL 2
#define DIM 16          // 2^NQ
#define BATCH 16
#define CH 256
#define HW 16384        // 128*128

typedef float floatx4 __attribute__((ext_vector_type(4)));

// ---------------- Kernel 1: per-(b,c) mean over H*W ----------------
// nt loads: x's pool read is stream-once (L3 does not retain it for scale,
// proven R5); avoid allocating these lines in L1/L2 on the way through.
__global__ void pool_kernel(const float* __restrict__ x, float* __restrict__ pooled) {
    const int bc = blockIdx.x;                       // 0..4095
    const floatx4* x4 = (const floatx4*)(x + (size_t)bc * HW);
    const int tid = threadIdx.x;                     // 256 threads
    float s = 0.f;
#pragma unroll
    for (int k = 0; k < 16; ++k) {                   // 16 float4 / thread
        floatx4 v = __builtin_nontemporal_load(&x4[tid + k * 256]);
        s += v.x + v.y + v.z + v.w;
    }
#pragma unroll
    for (int off = 32; off > 0; off >>= 1) s += __shfl_down(s, off, 64);
    __shared__ float partial[4];
    if ((tid & 63) == 0) partial[tid >> 6] = s;
    __syncthreads();
    if (tid == 0)
        pooled[bc] = (partial[0] + partial[1] + partial[2] + partial[3]) * (1.0f / HW);
}

// ---------------- Kernel 2: encoder + 4-qubit circuit + gates ----------------
// one block, 256 threads. Writes gates1p[b*CH+c] = 1 + sigmoid(...)
__global__ void gate_kernel(const float* __restrict__ pooled,
                            const float* __restrict__ enc_w,  // [NQ, CH]
                            const float* __restrict__ enc_b,  // [NQ]
                            const float* __restrict__ qw,     // [NL, NQ, 3]
                            const float* __restrict__ proj_w, // [CH, NQ]
                            const float* __restrict__ proj_b, // [CH]
                            float* __restrict__ gates1p) {
    __shared__ float sp[BATCH * CH];
    __shared__ float sz[BATCH][NQ];
    __shared__ float sref[BATCH][NQ];
    const int tid = threadIdx.x;

    for (int i = tid; i < BATCH * CH; i += 256) sp[i] = pooled[i];
    __syncthreads();

    // z = tanh(pooled @ enc_w^T + enc_b) : 64 (b,q) dots over 256
    if (tid < BATCH * NQ) {
        const int b = tid >> 2, q = tid & 3;
        float acc = enc_b[q];
        for (int c = 0; c < CH; ++c) acc += sp[b * CH + c] * enc_w[q * CH + c];
        sz[b][q] = tanhf(acc);
    }
    __syncthreads();

    // statevector simulation: one thread per batch
    if (tid < BATCH) {
        const int b = tid;
        float re[DIM], im[DIM];
#pragma unroll
        for (int i = 0; i < DIM; ++i) { re[i] = 0.f; im[i] = 0.f; }
        re[0] = 1.f;

        // AngleEmbedding: RY(z_w) on wire w (wire 0 = MSB)
        for (int w = 0; w < NQ; ++w) {
            const float a = sz[b][w] * 0.5f;
            const float cc = cosf(a), ss = sinf(a);
            const int m = 1 << (3 - w);
#pragma unroll
            for (int i = 0; i < DIM; ++i) {
                if (i & m) continue;
                const int j = i | m;
                const float r0 = cc * re[i] - ss * re[j];
                const float i0 = cc * im[i] - ss * im[j];
                const float r1 = ss * re[i] + cc * re[j];
                const float i1 = ss * im[i] + cc * im[j];
                re[i] = r0; im[i] = i0; re[j] = r1; im[j] = i1;
            }
        }
        // StronglyEntanglingLayers
        for (int l = 0; l < NL; ++l) {
            for (int w = 0; w < NQ; ++w) {
                const float phi = qw[(l * NQ + w) * 3 + 0];
                const float th  = qw[(l * NQ + w) * 3 + 1];
                const float om  = qw[(l * NQ + w) * 3 + 2];
                const float ct = cosf(0.5f * th), st = sinf(0.5f * th);
                const float am = -0.5f * (phi + om);
                const float ad =  0.5f * (phi - om);
                const float emr = cosf(am), emi = sinf(am);
                const float edr = cosf(ad), edi = sinf(ad);
                const float u00r =  emr * ct, u00i =  emi * ct;
                const float u01r = -edr * st, u01i = -edi * st;
                const float u10r =  edr * st, u10i = -edi * st;
                const float u11r =  emr * ct, u11i = -emi * ct;
                const int m = 1 << (3 - w);
#pragma unroll
                for (int i = 0; i < DIM; ++i) {
                    if (i & m) continue;
                    const int j = i | m;
                    const float ar = re[i], ai = im[i], br = re[j], bi = im[j];
                    re[i] = u00r * ar - u00i * ai + u01r * br - u01i * bi;
                    im[i] = u00r * ai + u00i * ar + u01r * bi + u01i * br;
                    re[j] = u10r * ar - u10i * ai + u11r * br - u11i * bi;
                    im[j] = u10r * ai + u10i * ar + u11r * bi + u11i * br;
                }
            }
            const int r = (l % (NQ - 1)) + 1;
            for (int w = 0; w < NQ; ++w) {
                const int t = (w + r) % NQ;
                const int cm = 1 << (3 - w);
                const int tm = 1 << (3 - t);
#pragma unroll
                for (int i = 0; i < DIM; ++i) {
                    if ((i & cm) && !(i & tm)) {
                        const int j = i | tm;
                        float tr = re[i]; re[i] = re[j]; re[j] = tr;
                        float ti = im[i]; im[i] = im[j]; im[j] = ti;
                    }
                }
            }
        }
        float p[DIM];
#pragma unroll
        for (int i = 0; i < DIM; ++i) p[i] = re[i] * re[i] + im[i] * im[i];
        for (int w = 0; w < NQ; ++w) {
            const int m = 1 << (3 - w);
            float ev = 0.f;
#pragma unroll
            for (int i = 0; i < DIM; ++i) ev += (i & m) ? -p[i] : p[i];
            sref[b][w] = ev;
        }
    }
    __syncthreads();

    // gates1p[b,c] = 1 + sigmoid(refined @ proj_w^T + proj_b)
    const int c = tid;
    const float pw0 = proj_w[c * NQ + 0], pw1 = proj_w[c * NQ + 1];
    const float pw2 = proj_w[c * NQ + 2], pw3 = proj_w[c * NQ + 3];
    const float pb = proj_b[c];
    for (int b = 0; b < BATCH; ++b) {
        const float acc = sref[b][0] * pw0 + sref[b][1] * pw1 +
                          sref[b][2] * pw2 + sref[b][3] * pw3 + pb;
        gates1p[b * CH + c] = 1.f + 1.f / (1.f + expf(-acc));
    }
}

// ---------------- Kernel 3: out = x * gates1p[b,c] ----------------
// R4-proven geometry: block owns 2048 consecutive float4 (within one (b,c)
// slice) -> g is block-uniform scalar load; 8 independent loads, 8 nt stores.
__global__ void scale_kernel(const float* __restrict__ x,
                             const float* __restrict__ gates1p,
                             float* __restrict__ out) {
    const floatx4* x4 = (const floatx4*)x;
    floatx4* o4 = (floatx4*)out;
    const int base = blockIdx.x * 2048 + threadIdx.x;
    const float g = gates1p[blockIdx.x >> 1];   // 2 blocks per (b,c)
    floatx4 v[8];
#pragma unroll
    for (int k = 0; k < 8; ++k) v[k] = x4[base + k * 256];
#pragma unroll
    for (int k = 0; k < 8; ++k) {
        v[k] *= g;
        __builtin_nontemporal_store(v[k], &o4[base + k * 256]);
    }
}

extern "C" void kernel_launch(void* const* d_in, const int* in_sizes, int n_in,
                              void* d_out, int out_size, void* d_ws, size_t ws_size,
                              hipStream_t stream) {
    const float* x      = (const float*)d_in[0];
    const float* enc_w  = (const float*)d_in[1];
    const float* enc_b  = (const float*)d_in[2];
    const float* qw     = (const float*)d_in[3];
    const float* proj_w = (const float*)d_in[4];
    const float* proj_b = (const float*)d_in[5];
    float* out = (float*)d_out;

    float* pooled  = (float*)d_ws;            // [16*256]
    float* gates1p = pooled + BATCH * CH;     // [16*256]

    pool_kernel<<<BATCH * CH, 256, 0, stream>>>(x, pooled);
    gate_kernel<<<1, 256, 0, stream>>>(pooled, enc_w, enc_b, qw, proj_w, proj_b, gates1p);
    scale_kernel<<<8192, 256, 0, stream>>>(x, gates1p, out);
}

// Round 12
// 149.091 us; speedup vs baseline: 3.1692x; 1.1295x over previous
//
#include <hip/hip_runtime.h>
#include <math.h>

#define NQ 4
#define NL 2
#define DIM 16          // 2^NQ
#define BATCH 16
#define CH 256
#define HW 16384        // 128*128

typedef float floatx4 __attribute__((ext_vector_type(4)));

// ---------------- Kernel 1: per-(b,c) mean over H*W ----------------
// Plain loads (NOT nontemporal): pool's pass leaves x resident in L3, which
// serves ~half of scale_kernel's re-read (R11 counter evidence: nt loads here
// cost +19 us by killing those hits).
__global__ void pool_kernel(const float* __restrict__ x, float* __restrict__ pooled) {
    const int bc = blockIdx.x;                       // 0..4095
    const floatx4* x4 = (const floatx4*)(x + (size_t)bc * HW);
    const int tid = threadIdx.x;                     // 256 threads
    float s = 0.f;
#pragma unroll
    for (int k = 0; k < 16; ++k) {                   // 16 float4 / thread
        floatx4 v = x4[tid + k * 256];
        s += v.x + v.y + v.z + v.w;
    }
#pragma unroll
    for (int off = 32; off > 0; off >>= 1) s += __shfl_down(s, off, 64);
    __shared__ float partial[4];
    if ((tid & 63) == 0) partial[tid >> 6] = s;
    __syncthreads();
    if (tid == 0)
        pooled[bc] = (partial[0] + partial[1] + partial[2] + partial[3]) * (1.0f / HW);
}

// ---------------- Kernel 2: encoder + 4-qubit circuit + gates ----------------
// one block, 256 threads. Writes gates1p[b*CH+c] = 1 + sigmoid(...)
__global__ void gate_kernel(const float* __restrict__ pooled,
                            const float* __restrict__ enc_w,  // [NQ, CH]
                            const float* __restrict__ enc_b,  // [NQ]
                            const float* __restrict__ qw,     // [NL, NQ, 3]
                            const float* __restrict__ proj_w, // [CH, NQ]
                            const float* __restrict__ proj_b, // [CH]
                            float* __restrict__ gates1p) {
    __shared__ float sp[BATCH * CH];
    __shared__ float sz[BATCH][NQ];
    __shared__ float sref[BATCH][NQ];
    const int tid = threadIdx.x;

    for (int i = tid; i < BATCH * CH; i += 256) sp[i] = pooled[i];
    __syncthreads();

    // z = tanh(pooled @ enc_w^T + enc_b) : 64 (b,q) dots over 256
    if (tid < BATCH * NQ) {
        const int b = tid >> 2, q = tid & 3;
        float acc = enc_b[q];
        for (int c = 0; c < CH; ++c) acc += sp[b * CH + c] * enc_w[q * CH + c];
        sz[b][q] = tanhf(acc);
    }
    __syncthreads();

    // statevector simulation: one thread per batch
    if (tid < BATCH) {
        const int b = tid;
        float re[DIM], im[DIM];
#pragma unroll
        for (int i = 0; i < DIM; ++i) { re[i] = 0.f; im[i] = 0.f; }
        re[0] = 1.f;

        // AngleEmbedding: RY(z_w) on wire w (wire 0 = MSB)
        for (int w = 0; w < NQ; ++w) {
            const float a = sz[b][w] * 0.5f;
            const float cc = cosf(a), ss = sinf(a);
            const int m = 1 << (3 - w);
#pragma unroll
            for (int i = 0; i < DIM; ++i) {
                if (i & m) continue;
                const int j = i | m;
                const float r0 = cc * re[i] - ss * re[j];
                const float i0 = cc * im[i] - ss * im[j];
                const float r1 = ss * re[i] + cc * re[j];
                const float i1 = ss * im[i] + cc * im[j];
                re[i] = r0; im[i] = i0; re[j] = r1; im[j] = i1;
            }
        }
        // StronglyEntanglingLayers
        for (int l = 0; l < NL; ++l) {
            for (int w = 0; w < NQ; ++w) {
                const float phi = qw[(l * NQ + w) * 3 + 0];
                const float th  = qw[(l * NQ + w) * 3 + 1];
                const float om  = qw[(l * NQ + w) * 3 + 2];
                const float ct = cosf(0.5f * th), st = sinf(0.5f * th);
                const float am = -0.5f * (phi + om);
                const float ad =  0.5f * (phi - om);
                const float emr = cosf(am), emi = sinf(am);
                const float edr = cosf(ad), edi = sinf(ad);
                const float u00r =  emr * ct, u00i =  emi * ct;
                const float u01r = -edr * st, u01i = -edi * st;
                const float u10r =  edr * st, u10i = -edi * st;
                const float u11r =  emr * ct, u11i = -emi * ct;
                const int m = 1 << (3 - w);
#pragma unroll
                for (int i = 0; i < DIM; ++i) {
                    if (i & m) continue;
                    const int j = i | m;
                    const float ar = re[i], ai = im[i], br = re[j], bi = im[j];
                    re[i] = u00r * ar - u00i * ai + u01r * br - u01i * bi;
                    im[i] = u00r * ai + u00i * ar + u01r * bi + u01i * br;
                    re[j] = u10r * ar - u10i * ai + u11r * br - u11i * bi;
                    im[j] = u10r * ai + u10i * ar + u11r * bi + u11i * br;
                }
            }
            const int r = (l % (NQ - 1)) + 1;
            for (int w = 0; w < NQ; ++w) {
                const int t = (w + r) % NQ;
                const int cm = 1 << (3 - w);
                const int tm = 1 << (3 - t);
#pragma unroll
                for (int i = 0; i < DIM; ++i) {
                    if ((i & cm) && !(i & tm)) {
                        const int j = i | tm;
                        float tr = re[i]; re[i] = re[j]; re[j] = tr;
                        float ti = im[i]; im[i] = im[j]; im[j] = ti;
                    }
                }
            }
        }
        float p[DIM];
#pragma unroll
        for (int i = 0; i < DIM; ++i) p[i] = re[i] * re[i] + im[i] * im[i];
        for (int w = 0; w < NQ; ++w) {
            const int m = 1 << (3 - w);
            float ev = 0.f;
#pragma unroll
            for (int i = 0; i < DIM; ++i) ev += (i & m) ? -p[i] : p[i];
            sref[b][w] = ev;
        }
    }
    __syncthreads();

    // gates1p[b,c] = 1 + sigmoid(refined @ proj_w^T + proj_b)
    const int c = tid;
    const float pw0 = proj_w[c * NQ + 0], pw1 = proj_w[c * NQ + 1];
    const float pw2 = proj_w[c * NQ + 2], pw3 = proj_w[c * NQ + 3];
    const float pb = proj_b[c];
    for (int b = 0; b < BATCH; ++b) {
        const float acc = sref[b][0] * pw0 + sref[b][1] * pw1 +
                          sref[b][2] * pw2 + sref[b][3] * pw3 + pb;
        gates1p[b * CH + c] = 1.f + 1.f / (1.f + expf(-acc));
    }
}

// ---------------- Kernel 3: out = x * gates1p[b,c] ----------------
// R5 champion geometry: reverse chunk order (freshest L3 lines first), block
// owns 2048 consecutive float4 within one (b,c) slice -> gate is a
// block-uniform scalar load; 8 independent loads, then 8 nt stores (out
// streams to HBM without evicting x).
__global__ void scale_kernel(const float* __restrict__ x,
                             const float* __restrict__ gates1p,
                             float* __restrict__ out) {
    const floatx4* x4 = (const floatx4*)x;
    floatx4* o4 = (floatx4*)out;
    const int chunk = 8191 - blockIdx.x;                // reverse order
    const int base = chunk * 2048 + threadIdx.x;        // float4 index
    const float g = gates1p[chunk >> 1];                // 2 chunks per (b,c)
    floatx4 v[8];
#pragma unroll
    for (int k = 0; k < 8; ++k) v[k] = x4[base + k * 256];
#pragma unroll
    for (int k = 0; k < 8; ++k) {
        v[k] *= g;
        __builtin_nontemporal_store(v[k], &o4[base + k * 256]);
    }
}

extern "C" void kernel_launch(void* const* d_in, const int* in_sizes, int n_in,
                              void* d_out, int out_size, void* d_ws, size_t ws_size,
                              hipStream_t stream) {
    const float* x      = (const float*)d_in[0];
    const float* enc_w  = (const float*)d_in[1];
    const float* enc_b  = (const float*)d_in[2];
    const float* qw     = (const float*)d_in[3];
    const float* proj_w = (const float*)d_in[4];
    const float* proj_b = (const float*)d_in[5];
    float* out = (float*)d_out;

    float* pooled  = (float*)d_ws;            // [16*256]
    float* gates1p = pooled + BATCH * CH;     // [16*256]

    pool_kernel<<<BATCH * CH, 256, 0, stream>>>(x, pooled);
    gate_kernel<<<1, 256, 0, stream>>>(pooled, enc_w, enc_b, qw, proj_w, proj_b, gates1p);
    scale_kernel<<<8192, 256, 0, stream>>>(x, gates1p, out);
}

// Round 13
// 144.941 us; speedup vs baseline: 3.2599x; 1.0286x over previous
//
#include <hip/hip_runtime.h>
#include <math.h>

#define NQ 4
#define NL 2
#define DIM 16          // 2^NQ
#define BATCH 16
#define CH 256
#define HW 16384        // 128*128

typedef float floatx4 __attribute__((ext_vector_type(4)));

// ---------------- Kernel 1: per-(b,c) mean over H*W ----------------
// Plain loads (NOT nontemporal): pool's pass leaves x resident in L3, which
// serves ~half of scale_kernel's re-read (R11: nt loads here cost +19 us).
__global__ void pool_kernel(const float* __restrict__ x, float* __restrict__ pooled) {
    const int bc = blockIdx.x;                       // 0..4095
    const floatx4* x4 = (const floatx4*)(x + (size_t)bc * HW);
    const int tid = threadIdx.x;                     // 256 threads
    float s = 0.f;
#pragma unroll
    for (int k = 0; k < 16; ++k) {                   // 16 float4 / thread
        floatx4 v = x4[tid + k * 256];
        s += v.x + v.y + v.z + v.w;
    }
#pragma unroll
    for (int off = 32; off > 0; off >>= 1) s += __shfl_down(s, off, 64);
    __shared__ float partial[4];
    if ((tid & 63) == 0) partial[tid >> 6] = s;
    __syncthreads();
    if (tid == 0)
        pooled[bc] = (partial[0] + partial[1] + partial[2] + partial[3]) * (1.0f / HW);
}

// ---------------- Kernel 2: gate, one block per batch (16 blocks) ----------
// Wave-per-qubit dot (4 waves x 64-lane shuffle reduce) replaces the serial
// 256-iter per-thread loop of the 1-block version; circuit on thread 0
// (structure numerically proven in R7's fused kernel).
__global__ void gate_kernel16(const float* __restrict__ pooled,
                              const float* __restrict__ enc_w,  // [NQ, CH]
                              const float* __restrict__ enc_b,  // [NQ]
                              const float* __restrict__ qw,     // [NL, NQ, 3]
                              const float* __restrict__ proj_w, // [CH, NQ]
                              const float* __restrict__ proj_b, // [CH]
                              float* __restrict__ gates1p) {
    const int b = blockIdx.x;              // batch
    const int tid = threadIdx.x;           // 256 threads = 4 waves

    __shared__ float sz[NQ];
    __shared__ float sevs[NQ];

    // z[q] = tanh(dot(pooled[b,:], enc_w[q,:]) + enc_b[q]); wave q does qubit q
    {
        const int q = tid >> 6, lane = tid & 63;
        const float* prow = pooled + b * CH;
        float acc = 0.f;
#pragma unroll
        for (int j = 0; j < 4; ++j) {
            const int c = lane * 4 + j;
            acc += prow[c] * enc_w[q * CH + c];
        }
#pragma unroll
        for (int off = 32; off > 0; off >>= 1) acc += __shfl_down(acc, off, 64);
        if (lane == 0) sz[q] = tanhf(acc + enc_b[q]);
    }
    __syncthreads();

    // 4-qubit statevector on thread 0
    if (tid == 0) {
        float re[DIM], im[DIM];
#pragma unroll
        for (int i = 0; i < DIM; ++i) { re[i] = 0.f; im[i] = 0.f; }
        re[0] = 1.f;

        // AngleEmbedding: RY(z_w) on wire w (wire 0 = MSB)
        for (int w = 0; w < NQ; ++w) {
            const float a = sz[w] * 0.5f;
            const float cc = cosf(a), ss = sinf(a);
            const int m = 1 << (3 - w);
#pragma unroll
            for (int i = 0; i < DIM; ++i) {
                if (i & m) continue;
                const int j = i | m;
                const float r0 = cc * re[i] - ss * re[j];
                const float i0 = cc * im[i] - ss * im[j];
                const float r1 = ss * re[i] + cc * re[j];
                const float i1 = ss * im[i] + cc * im[j];
                re[i] = r0; im[i] = i0; re[j] = r1; im[j] = i1;
            }
        }
        // StronglyEntanglingLayers
        for (int l = 0; l < NL; ++l) {
            for (int w = 0; w < NQ; ++w) {
                const float phi = qw[(l * NQ + w) * 3 + 0];
                const float th  = qw[(l * NQ + w) * 3 + 1];
                const float om  = qw[(l * NQ + w) * 3 + 2];
                const float ct = cosf(0.5f * th), st = sinf(0.5f * th);
                const float am = -0.5f * (phi + om);
                const float ad =  0.5f * (phi - om);
                const float emr = cosf(am), emi = sinf(am);
                const float edr = cosf(ad), edi = sinf(ad);
                const float u00r =  emr * ct, u00i =  emi * ct;
                const float u01r = -edr * st, u01i = -edi * st;
                const float u10r =  edr * st, u10i = -edi * st;
                const float u11r =  emr * ct, u11i = -emi * ct;
                const int m = 1 << (3 - w);
#pragma unroll
                for (int i = 0; i < DIM; ++i) {
                    if (i & m) continue;
                    const int j = i | m;
                    const float ar = re[i], ai = im[i], br = re[j], bi = im[j];
                    re[i] = u00r * ar - u00i * ai + u01r * br - u01i * bi;
                    im[i] = u00r * ai + u00i * ar + u01r * bi + u01i * br;
                    re[j] = u10r * ar - u10i * ai + u11r * br - u11i * bi;
                    im[j] = u10r * ai + u10i * ar + u11r * bi + u11i * br;
                }
            }
            const int r = (l % (NQ - 1)) + 1;
            for (int w = 0; w < NQ; ++w) {
                const int t = (w + r) % NQ;
                const int cm = 1 << (3 - w);
                const int tm = 1 << (3 - t);
#pragma unroll
                for (int i = 0; i < DIM; ++i) {
                    if ((i & cm) && !(i & tm)) {
                        const int j = i | tm;
                        float tr = re[i]; re[i] = re[j]; re[j] = tr;
                        float ti = im[i]; im[i] = im[j]; im[j] = ti;
                    }
                }
            }
        }
        float p[DIM];
#pragma unroll
        for (int i = 0; i < DIM; ++i) p[i] = re[i] * re[i] + im[i] * im[i];
        for (int w = 0; w < NQ; ++w) {
            const int m = 1 << (3 - w);
            float ev = 0.f;
#pragma unroll
            for (int i = 0; i < DIM; ++i) ev += (i & m) ? -p[i] : p[i];
            sevs[w] = ev;
        }
    }
    __syncthreads();

    // gates1p[b,c] = 1 + sigmoid(refined @ proj_w^T + proj_b); c = tid
    {
        const int c = tid;
        const float acc = sevs[0] * proj_w[c * NQ + 0] + sevs[1] * proj_w[c * NQ + 1] +
                          sevs[2] * proj_w[c * NQ + 2] + sevs[3] * proj_w[c * NQ + 3] +
                          proj_b[c];
        gates1p[b * CH + c] = 1.f + 1.f / (1.f + expf(-acc));
    }
}

// ---------------- Kernel 3: out = x * gates1p[b,c] ----------------
// One block per (b,c) slice (4096 blocks), reverse order (freshest L3 lines
// first). 16 independent loads issued before any store (16-deep MLP), g is a
// block-uniform scalar load, nt stores keep out from evicting x.
__global__ void scale_kernel(const float* __restrict__ x,
                             const float* __restrict__ gates1p,
                             float* __restrict__ out) {
    const int slice = 4095 - blockIdx.x;                 // reverse order
    const int tid = threadIdx.x;
    const floatx4* x4 = (const floatx4*)(x + (size_t)slice * HW);
    floatx4* o4 = (floatx4*)(out + (size_t)slice * HW);
    const float g = gates1p[slice];                      // scalar (block-uniform)
    floatx4 v[16];
#pragma unroll
    for (int k = 0; k < 16; ++k) v[k] = x4[tid + k * 256];
#pragma unroll
    for (int k = 0; k < 16; ++k) {
        v[k] *= g;
        __builtin_nontemporal_store(v[k], &o4[tid + k * 256]);
    }
}

extern "C" void kernel_launch(void* const* d_in, const int* in_sizes, int n_in,
                              void* d_out, int out_size, void* d_ws, size_t ws_size,
                              hipStream_t stream) {
    const float* x      = (const float*)d_in[0];
    const float* enc_w  = (const float*)d_in[1];
    const float* enc_b  = (const float*)d_in[2];
    const float* qw     = (const float*)d_in[3];
    const float* proj_w = (const float*)d_in[4];
    const float* proj_b = (const float*)d_in[5];
    float* out = (float*)d_out;

    float* pooled  = (float*)d_ws;            // [16*256]
    float* gates1p = pooled + BATCH * CH;     // [16*256]

    pool_kernel<<<BATCH * CH, 256, 0, stream>>>(x, pooled);
    gate_kernel16<<<BATCH, 256, 0, stream>>>(pooled, enc_w, enc_b, qw,
                                             proj_w, proj_b, gates1p);
    scale_kernel<<<BATCH * CH, 256, 0, stream>>>(x, gates1p, out);
}